// Round 1
// baseline (1768.883 us; speedup 1.0000x reference)
//
#include <hip/hip_runtime.h>

// Problem constants (specialized for this reference):
//   N = 50000 nodes, E = 1,000,000 edges, F = 128, HF = 256 (num_heads*feat)
static constexpr int F  = 128;
static constexpr int HF = 256;

// ---------------- Kernel 1: histogram of destination nodes ----------------
__global__ __launch_bounds__(256) void hist_kernel(const int* __restrict__ nbrs,
                                                   int* __restrict__ counts,
                                                   int E, int N) {
    int e = blockIdx.x * 256 + threadIdx.x;
    if (e < E) {
        int dst = nbrs[2 * e];
        if ((unsigned)dst < (unsigned)N) atomicAdd(&counts[dst], 1);
    }
}

// ---------------- Kernel 2: single-block chunked exclusive scan -----------
__global__ __launch_bounds__(256) void scan_kernel(const int* __restrict__ counts,
                                                   int* __restrict__ offsets,
                                                   int* __restrict__ cursor,
                                                   int n) {
    __shared__ int sums[256];
    int tid = threadIdx.x;
    int chunk = (n + 255) >> 8;
    int start = tid * chunk;
    int end = min(start + chunk, n);
    int s = 0;
    for (int i = start; i < end; ++i) s += counts[i];
    sums[tid] = s;
    __syncthreads();
    // Hillis-Steele inclusive scan over the 256 per-thread sums
    for (int off = 1; off < 256; off <<= 1) {
        int v = (tid >= off) ? sums[tid - off] : 0;
        __syncthreads();
        sums[tid] += v;
        __syncthreads();
    }
    int pre = (tid > 0) ? sums[tid - 1] : 0;  // exclusive prefix of my chunk
    for (int i = start; i < end; ++i) {
        offsets[i] = pre;
        cursor[i]  = pre;
        pre += counts[i];
    }
    if (start < n && end == n) offsets[n] = pre;  // total
}

// ---------------- Kernel 3: counting-sort placement of edge ids -----------
__global__ __launch_bounds__(256) void place_kernel(const int* __restrict__ nbrs,
                                                    int* __restrict__ cursor,
                                                    int* __restrict__ sorted,
                                                    int E, int N) {
    int e = blockIdx.x * 256 + threadIdx.x;
    if (e < E) {
        int dst = nbrs[2 * e];
        if ((unsigned)dst < (unsigned)N) {
            int pos = atomicAdd(&cursor[dst], 1);
            sorted[pos] = e;
        }
    }
}

// ---------------- Kernel 4: segment reduce (one wave per node) ------------
// lane owns 4 contiguous channels (float4); each edge row = 64 float4 = 1 KB,
// fully coalesced per wave.
__global__ __launch_bounds__(256) void reduce_kernel(const float4* __restrict__ sv,
                                                     const int* __restrict__ sorted,
                                                     const int* __restrict__ offsets,
                                                     float4* __restrict__ accv,
                                                     int N) {
    int node = blockIdx.x * 4 + (threadIdx.x >> 6);
    int lane = threadIdx.x & 63;
    if (node >= N) return;
    int beg = offsets[node];
    int end = offsets[node + 1];
    float ax = 0.f, ay = 0.f, az = 0.f, aw = 0.f;
    for (int i = beg; i < end; ++i) {
        int e = sorted[i];
        float4 v = sv[(size_t)e * 64 + lane];
        ax += v.x; ay += v.y; az += v.z; aw += v.w;
    }
    float4 r; r.x = ax; r.y = ay; r.z = az; r.w = aw;
    accv[(size_t)node * 64 + lane] = r;
}

// ---------------- Kernel 5: transpose W [128][256] -> Wt [256][128] -------
__global__ void transpose_w(const float* __restrict__ W, float* __restrict__ Wt) {
    int c = threadIdx.x;                        // 0..127 (feat col)
    int k = blockIdx.x * 2 + threadIdx.y;       // 0..255 (HF row)
    Wt[k * F + c] = W[c * HF + k];              // coalesced write
}

// ---------------- Kernel 6: out = x_i + acc @ Wt + b ----------------------
// Wave = 64 cols x 16 rows, K=256 in chunks of 16.
// W chunk lives in 16 VGPRs/lane (coalesced, L2-hot loads of Wt).
// A chunks are wave-uniform -> forced scalar loads via readfirstlane.
__global__ __launch_bounds__(256) void gemm_kernel(const float* __restrict__ acc,
                                                   const float* __restrict__ Wt,
                                                   const float* __restrict__ x_i,
                                                   const float* __restrict__ bias,
                                                   float* __restrict__ out,
                                                   int M) {
    int tid  = threadIdx.x;
    int wave = tid >> 6;
    int lane = tid & 63;
    int col  = (wave & 1) * 64 + lane;                        // 0..127
    int row0 = blockIdx.x * 32 + (wave >> 1) * 16;
    row0 = __builtin_amdgcn_readfirstlane(row0);              // force SGPR
    if (row0 >= M) return;

    float accr[16];
#pragma unroll
    for (int r = 0; r < 16; ++r) accr[r] = 0.f;

    for (int kc = 0; kc < HF; kc += 16) {
        float w[16];
#pragma unroll
        for (int i = 0; i < 16; ++i) w[i] = Wt[(kc + i) * F + col];
#pragma unroll
        for (int r = 0; r < 16; ++r) {
            const float* arow = acc + (size_t)(row0 + r) * HF + kc;
#pragma unroll
            for (int i = 0; i < 16; ++i)
                accr[r] = fmaf(arow[i], w[i], accr[r]);
        }
    }

    float bv = bias[col];
#pragma unroll
    for (int r = 0; r < 16; ++r) {
        size_t idx = (size_t)(row0 + r) * F + col;
        out[idx] = x_i[idx] + accr[r] + bv;
    }
}

// --------------------------------------------------------------------------
extern "C" void kernel_launch(void* const* d_in, const int* in_sizes, int n_in,
                              void* d_out, int out_size, void* d_ws, size_t ws_size,
                              hipStream_t stream) {
    const int*   nbrs     = (const int*)d_in[0];
    const float* x_i      = (const float*)d_in[1];
    const float* scaled_v = (const float*)d_in[2];
    const float* W        = (const float*)d_in[3];
    const float* b        = (const float*)d_in[4];
    float*       out      = (float*)d_out;

    const int E = in_sizes[0] / 2;   // 1,000,000
    const int N = in_sizes[1] / F;   // 50,000

    // Workspace layout (16B aligned slices); total ~55.8 MB
    char* ws = (char*)d_ws;
    size_t off = 0;
    auto alloc = [&](size_t bytes) {
        char* p = ws + off;
        off += (bytes + 15) & ~(size_t)15;
        return p;
    };
    float* acc     = (float*)alloc((size_t)N * HF * sizeof(float)); // 51.2 MB
    int*   counts  = (int*)  alloc((size_t)N * sizeof(int));
    int*   offsets = (int*)  alloc((size_t)(N + 1) * sizeof(int));
    int*   cursor  = (int*)  alloc((size_t)N * sizeof(int));
    int*   sorted  = (int*)  alloc((size_t)E * sizeof(int));        // 4 MB
    float* Wt      = (float*)alloc((size_t)HF * F * sizeof(float)); // 131 KB

    hipMemsetAsync(counts, 0, (size_t)N * sizeof(int), stream);

    hist_kernel <<<(E + 255) / 256, 256, 0, stream>>>(nbrs, counts, E, N);
    scan_kernel <<<1, 256, 0, stream>>>(counts, offsets, cursor, N);
    place_kernel<<<(E + 255) / 256, 256, 0, stream>>>(nbrs, cursor, sorted, E, N);
    reduce_kernel<<<(N + 3) / 4, 256, 0, stream>>>((const float4*)scaled_v, sorted,
                                                   offsets, (float4*)acc, N);
    transpose_w <<<128, dim3(128, 2), 0, stream>>>(W, Wt);
    gemm_kernel <<<(N + 31) / 32, 256, 0, stream>>>(acc, Wt, x_i, b, out, N);
}